// Round 7
// baseline (780.551 us; speedup 1.0000x reference)
//
#include <hip/hip_runtime.h>
#include <cmath>

#define IN_CH 128
#define OUT_CH 128
#define KDIM 512           // Z row: x(128) | sum(128) | mean(128) | max(128)
#define NGEMM 384          // W^T rows: permuted (colgroup, wavehalf, section, ocol16)
#define GBM 256            // gemm rows per block
#define GBN 192            // gemm cols (W^T rows) per block

typedef __attribute__((ext_vector_type(8))) short bfrag;   // 8 bf16 in 4 VGPRs
typedef __attribute__((ext_vector_type(4))) float f32x4;

// float -> bf16 round-to-nearest-even (bit pattern)
__device__ __forceinline__ unsigned short f2bf(float f) {
    unsigned int u = __float_as_uint(f);
    return (unsigned short)((u + 0x7FFFu + ((u >> 16) & 1u)) >> 16);
}
__device__ __forceinline__ float bf2f(unsigned short h) {
    return __uint_as_float(((unsigned int)h) << 16);
}

// async 16B global->LDS (wave-level; LDS side is lane-linear base+lane*16)
__device__ __forceinline__ void gl2lds16(const void* g, void* l) {
    __builtin_amdgcn_global_load_lds(
        (const __attribute__((address_space(1))) unsigned int*)g,
        (__attribute__((address_space(3))) unsigned int*)l, 16, 0, 0);
}

// ---------------- CSR build ----------------

__global__ void degree_kernel(const int* __restrict__ ei, int* __restrict__ degree, int E) {
    int e = blockIdx.x * blockDim.x + threadIdx.x;
    if (e < E) atomicAdd(&degree[ei[E + e]], 1);
}

__global__ __launch_bounds__(1024) void scan_kernel(const int* __restrict__ degree,
                                                    int* __restrict__ offsets,
                                                    float* __restrict__ logsum, int n) {
    const int T = 1024;
    int tid = threadIdx.x;
    int chunk = (n + T - 1) / T;
    int beg = min(tid * chunk, n);
    int end = min(beg + chunk, n);
    int s = 0;
    float ls = 0.f;
    for (int i = beg; i < end; ++i) {
        int d = degree[i];
        s += d;
        ls += logf((float)d + 2.0f);   // == log1p(d+1)
    }
    __shared__ int part[T];
    __shared__ float fl[T];
    part[tid] = s;
    fl[tid] = ls;
    __syncthreads();
    for (int off = 1; off < T; off <<= 1) {
        int v = (tid >= off) ? part[tid - off] : 0;
        __syncthreads();
        part[tid] += v;
        __syncthreads();
    }
    for (int off = T / 2; off > 0; off >>= 1) {
        if (tid < off) fl[tid] += fl[tid + off];
        __syncthreads();
    }
    if (tid == 0) logsum[0] = fl[0];
    int prefix = (tid == 0) ? 0 : part[tid - 1];
    for (int i = beg; i < end; ++i) {
        offsets[i] = prefix;
        prefix += degree[i];
    }
    if (tid == T - 1) offsets[n] = prefix;
}

// fill bumps offsets[] in place; afterwards offsets[v] == end of v's segment.
// agg recovers beg = end - degree[v]. (No cursor array, no extra memset.)
__global__ void fill_kernel(const int* __restrict__ ei, int* __restrict__ offsets,
                            int* __restrict__ csr_src, int E) {
    int e = blockIdx.x * blockDim.x + threadIdx.x;
    if (e < E) {
        int src = ei[e];
        int dst = ei[E + e];
        int pos = atomicAdd(&offsets[dst], 1);
        csr_src[pos] = src;
    }
}

// ---------------- Aggregation: one WAVE per node, EDGE-PAIR float4 gathers ---------
// lane = (h, c4): h = lane>>5 selects edge of a pair, c4 = lane&31 selects 4 channels.
// 16 B/lane gathers (vs 8 B before) halve the gather instruction count on the
// ~11 B/cyc/CU vector-memory pipe. Cross-half combine via __shfl_xor(.,32).

__global__ __launch_bounds__(256) void agg_kernel(const float* __restrict__ x,
                                                  const int* __restrict__ csr_src,
                                                  const int* __restrict__ offsets,
                                                  const int* __restrict__ degree,
                                                  const float* __restrict__ logsum,
                                                  unsigned short* __restrict__ Zhi,
                                                  unsigned short* __restrict__ Zlo,
                                                  float* __restrict__ ampv,
                                                  float* __restrict__ attv,
                                                  int N, int Mpad) {
    int node = (blockIdx.x * 256 + threadIdx.x) >> 6;
    int lane = threadIdx.x & 63;
    if (node >= Mpad) return;
    int h = lane >> 5;
    int c4 = lane & 31;
    long zbase = (long)node * KDIM + c4 * 4;
    if (node >= N) {   // pad rows: zero so GEMM reads are harmless
        if (h == 0) {
            uint2 z = make_uint2(0u, 0u);
            #pragma unroll
            for (int sec = 0; sec < 4; ++sec) {
                *(uint2*)&Zhi[zbase + sec * 128] = z;
                *(uint2*)&Zlo[zbase + sec * 128] = z;
            }
        }
        return;
    }
    int deg = degree[node];
    int end = offsets[node];          // post-fill end of segment
    int beg = end - deg;
    const float NEG = -3.402823466e38f;
    float4 s[4], m[4];
    #pragma unroll
    for (int u = 0; u < 4; ++u) {
        s[u] = make_float4(0.f, 0.f, 0.f, 0.f);
        m[u] = make_float4(NEG, NEG, NEG, NEG);
    }
    int i = beg;
    for (; i + 8 <= end; i += 8) {      // 4 pair-slots = 8 edges, 4 indep chains
        int idx[4];
        #pragma unroll
        for (int u = 0; u < 4; ++u) idx[u] = csr_src[i + u * 2 + h];
        float4 v[4];
        #pragma unroll
        for (int u = 0; u < 4; ++u) v[u] = *(const float4*)&x[(long)idx[u] * IN_CH + c4 * 4];
        #pragma unroll
        for (int u = 0; u < 4; ++u) {
            s[u].x += v[u].x; s[u].y += v[u].y; s[u].z += v[u].z; s[u].w += v[u].w;
            m[u].x = fmaxf(m[u].x, v[u].x); m[u].y = fmaxf(m[u].y, v[u].y);
            m[u].z = fmaxf(m[u].z, v[u].z); m[u].w = fmaxf(m[u].w, v[u].w);
        }
    }
    for (; i < end; i += 2) {           // tail pairs (upper half may be inactive)
        int e = i + h;
        if (e < end) {
            int idx = csr_src[e];
            float4 v = *(const float4*)&x[(long)idx * IN_CH + c4 * 4];
            s[0].x += v.x; s[0].y += v.y; s[0].z += v.z; s[0].w += v.w;
            m[0].x = fmaxf(m[0].x, v.x); m[0].y = fmaxf(m[0].y, v.y);
            m[0].z = fmaxf(m[0].z, v.z); m[0].w = fmaxf(m[0].w, v.w);
        }
    }
    float4 sum, mx;
    sum.x = (s[0].x + s[1].x) + (s[2].x + s[3].x);
    sum.y = (s[0].y + s[1].y) + (s[2].y + s[3].y);
    sum.z = (s[0].z + s[1].z) + (s[2].z + s[3].z);
    sum.w = (s[0].w + s[1].w) + (s[2].w + s[3].w);
    mx.x = fmaxf(fmaxf(m[0].x, m[1].x), fmaxf(m[2].x, m[3].x));
    mx.y = fmaxf(fmaxf(m[0].y, m[1].y), fmaxf(m[2].y, m[3].y));
    mx.z = fmaxf(fmaxf(m[0].z, m[1].z), fmaxf(m[2].z, m[3].z));
    mx.w = fmaxf(fmaxf(m[0].w, m[1].w), fmaxf(m[2].w, m[3].w));
    // cross-half combine
    sum.x += __shfl_xor(sum.x, 32); sum.y += __shfl_xor(sum.y, 32);
    sum.z += __shfl_xor(sum.z, 32); sum.w += __shfl_xor(sum.w, 32);
    mx.x = fmaxf(mx.x, __shfl_xor(mx.x, 32)); mx.y = fmaxf(mx.y, __shfl_xor(mx.y, 32));
    mx.z = fmaxf(mx.z, __shfl_xor(mx.z, 32)); mx.w = fmaxf(mx.w, __shfl_xor(mx.w, 32));

    float inv = 1.0f / fmaxf((float)deg, 1.0f);
    float4 mean = make_float4(sum.x * inv, sum.y * inv, sum.z * inv, sum.w * inv);
    if (deg == 0) mx = make_float4(0.f, 0.f, 0.f, 0.f);
    float4 xv = *(const float4*)&x[(long)node * IN_CH + c4 * 4];

    if (h == 0) {
        float4 secs[4] = { xv, sum, mean, mx };
        #pragma unroll
        for (int sec = 0; sec < 4; ++sec) {
            float4 v = secs[sec];
            unsigned short hx = f2bf(v.x), hy = f2bf(v.y), hz = f2bf(v.z), hw = f2bf(v.w);
            uint2 hi = make_uint2((unsigned)hx | ((unsigned)hy << 16),
                                  (unsigned)hz | ((unsigned)hw << 16));
            uint2 lo = make_uint2((unsigned)f2bf(v.x - bf2f(hx)) | ((unsigned)f2bf(v.y - bf2f(hy)) << 16),
                                  (unsigned)f2bf(v.z - bf2f(hz)) | ((unsigned)f2bf(v.w - bf2f(hw)) << 16));
            *(uint2*)&Zhi[zbase + sec * 128] = hi;
            *(uint2*)&Zlo[zbase + sec * 128] = lo;
        }
    }
    if (lane == 0) {
        float ref = fmaxf(logsum[0] / (float)N, 1.0f);
        float dt = log1pf((float)deg + 1.0f);
        ampv[node] = dt / ref;
        attv[node] = ref / fmaxf(dt, 1e-6f);
    }
}

// ---------------- Weight build: permuted row-major W^T, bf16 hi/lo -----------------
// jp = cg*96 + s16*16 + r16, s16 in [0,6): wn2 = s16/3, sec = s16%3,
// ocol = cg*32 + wn2*16 + r16.

__global__ void wbuild_kernel(const float* __restrict__ Wmsg, const float* __restrict__ Wroot,
                              unsigned short* __restrict__ Whi, unsigned short* __restrict__ Wlo) {
    int idx = blockIdx.x * 256 + threadIdx.x;
    if (idx >= NGEMM * KDIM) return;
    int jp = idx >> 9;       // 0..383
    int k = idx & 511;
    int cg = jp / 96;
    int rem = jp - cg * 96;
    int s16 = rem >> 4;
    int r16 = rem & 15;
    int wn2 = s16 / 3;
    int sec = s16 - wn2 * 3;
    int ocol = cg * 32 + wn2 * 16 + r16;
    float v;
    if (k < 128) {
        v = (sec == 0) ? Wroot[ocol * 128 + k] : 0.f;
    } else {
        int a = (k - 128) >> 7;
        int c = (k - 128) & 127;
        v = Wmsg[ocol * 1152 + (a * 3 + sec) * 128 + c];
    }
    unsigned short h = f2bf(v);
    Whi[idx] = h;
    Wlo[idx] = f2bf(v - bf2f(h));
}

// ---------------- MFMA GEMM: minimize staged bytes ---------------------------------
// Staging model (measured r6): time = staged_bytes / ~6.8 TB/s device-wide.
// BM=256, BN=192, BK=32: staged = 102.5MB*2 (A) + 0.786MB*196 (B) = 359 MB.
// hi+lo staged ONCE per K-tile; all 3 products (ah*bh, ah*bl, al*bh) from LDS.
// 1024 thr = 16 waves; wave tile 64 rows x 48 cols (4x3 tiles), acc = 48 AGPR.
// LDS 56 KB single-buffer: Ahi[0,8192) Alo[8192,16384) Bhi[16384,22528)
// Blo[22528,28672) (ushort units). 3.5 gl2lds16/thread/iter, zero per-iter addr math.

__global__ __launch_bounds__(1024, 8) void gemm_kernel(const unsigned short* __restrict__ Zhi,
                                                       const unsigned short* __restrict__ Zlo,
                                                       const unsigned short* __restrict__ Whi,
                                                       const unsigned short* __restrict__ Wlo,
                                                       const float* __restrict__ ampv,
                                                       const float* __restrict__ attv,
                                                       const float* __restrict__ bmsg,
                                                       const float* __restrict__ broot,
                                                       float* __restrict__ out, int M) {
    __shared__ unsigned short lds[28672];   // 56 KB
    const int tid = threadIdx.x;
    const int w = tid >> 6;                 // 0..15
    const int lane = tid & 63;
    const int r16 = lane & 15, q = lane >> 4;
    const int wm = w >> 2, wn = w & 3;
    const int row0 = blockIdx.x * GBM;
    const int cg2 = blockIdx.y;             // 0..1

    // staging sources (ushort units); chunk c = l*1024 + tid, LDS dst = c*16 B
    const unsigned short* sAh = Zhi + (long)(row0 + w * 16 + r16) * KDIM + q * 8;
    const unsigned short* sAl = Zlo + (long)(row0 + w * 16 + r16) * KDIM + q * 8;
    const unsigned short* sB2 = (w < 12)
        ? Whi + (long)(cg2 * GBN + w * 16 + r16) * KDIM + q * 8
        : Wlo + (long)(cg2 * GBN + (w - 12) * 16 + r16) * KDIM + q * 8;
    const unsigned short* sB3 = Wlo + (long)(cg2 * GBN + (4 + w) * 16 + r16) * KDIM + q * 8;
    char* ldsb = (char*)lds;
    const int d0 = tid * 16, d1 = (1024 + tid) * 16, d2 = (2048 + tid) * 16, d3 = (3072 + tid) * 16;

    f32x4 acc[4][3] = {};
    const int jtb = (wn >> 1) * 6 + (wn & 1) * 3;

    #pragma unroll 1
    for (int it = 0; it < 16; ++it) {
        if (it) __syncthreads();            // WAR: prior iter's ds_reads done
        gl2lds16(sAh, ldsb + d0);
        gl2lds16(sAl, ldsb + d1);
        gl2lds16(sB2, ldsb + d2);
        if (w < 8) gl2lds16(sB3, ldsb + d3);
        sAh += 32; sAl += 32; sB2 += 32; sB3 += 32;
        __syncthreads();                    // staging visible

        bfrag ah[4], al[4], bh[3], bl[3];
        #pragma unroll
        for (int mt = 0; mt < 4; ++mt) {
            int ch = ((wm * 4 + mt) * 64 + lane) * 8;
            ah[mt] = *(const bfrag*)&lds[ch];
            al[mt] = *(const bfrag*)&lds[8192 + ch];
        }
        #pragma unroll
        for (int nt = 0; nt < 3; ++nt) {
            int chb = ((jtb + nt) * 64 + lane) * 8;
            bh[nt] = *(const bfrag*)&lds[16384 + chb];
            bl[nt] = *(const bfrag*)&lds[22528 + chb];
        }
        #pragma unroll
        for (int nt = 0; nt < 3; ++nt) {
            #pragma unroll
            for (int mt = 0; mt < 4; ++mt) {
                acc[mt][nt] = __builtin_amdgcn_mfma_f32_16x16x32_bf16(ah[mt], bh[nt], acc[mt][nt], 0, 0, 0);
                acc[mt][nt] = __builtin_amdgcn_mfma_f32_16x16x32_bf16(ah[mt], bl[nt], acc[mt][nt], 0, 0, 0);
                acc[mt][nt] = __builtin_amdgcn_mfma_f32_16x16x32_bf16(al[mt], bh[nt], acc[mt][nt], 0, 0, 0);
            }
        }
    }

    // fused epilogue: C/D layout col=lane&15, row=q*4+r (verified m89/m91)
    const int col = (cg2 * 2 + (wn >> 1)) * 32 + (wn & 1) * 16 + r16;
    const float bias = bmsg[col] + broot[col];
    #pragma unroll
    for (int mt = 0; mt < 4; ++mt) {
        #pragma unroll
        for (int r = 0; r < 4; ++r) {
            int row = row0 + wm * 64 + mt * 16 + q * 4 + r;
            if (row < M) {
                float v = acc[mt][0][r]
                        + ampv[row] * acc[mt][1][r]
                        + attv[row] * acc[mt][2][r] + bias;
                out[(long)row * OUT_CH + col] = v;
            }
        }
    }
}

// ---------------- Launch ----------------

extern "C" void kernel_launch(void* const* d_in, const int* in_sizes, int n_in,
                              void* d_out, int out_size, void* d_ws, size_t ws_size,
                              hipStream_t stream) {
    const float* x     = (const float*)d_in[0];
    const int*   ei    = (const int*)d_in[1];
    const float* Wmsg  = (const float*)d_in[2];
    const float* bmsg  = (const float*)d_in[3];
    const float* Wroot = (const float*)d_in[4];
    const float* broot = (const float*)d_in[5];
    float* out = (float*)d_out;

    int N = in_sizes[0] / IN_CH;           // 50000
    int E = in_sizes[1] / 2;               // 600000
    int Mb = (N + GBM - 1) / GBM;          // 196
    int Mpad = Mb * GBM;                   // 50176

    char* ws = (char*)d_ws;
    size_t off = 0;
    auto alloc = [&](size_t bytes) -> void* {
        void* p = ws + off;
        off = (off + bytes + 255) & ~(size_t)255;
        return p;
    };
    int* degree  = (int*)alloc((size_t)N * 4);
    int* offsets = (int*)alloc((size_t)(N + 1) * 4);
    float* logsum = (float*)alloc(4);
    int* csr_src = (int*)alloc((size_t)E * 4);
    unsigned short* Whi = (unsigned short*)alloc((size_t)NGEMM * KDIM * 2);
    unsigned short* Wlo = (unsigned short*)alloc((size_t)NGEMM * KDIM * 2);
    unsigned short* Zhi = (unsigned short*)alloc((size_t)Mpad * KDIM * 2);
    unsigned short* Zlo = (unsigned short*)alloc((size_t)Mpad * KDIM * 2);
    float* ampv = (float*)alloc((size_t)N * 4);
    float* attv = (float*)alloc((size_t)N * 4);

    hipMemsetAsync(degree, 0, (size_t)N * 4, stream);

    degree_kernel<<<(E + 255) / 256, 256, 0, stream>>>(ei, degree, E);
    scan_kernel<<<1, 1024, 0, stream>>>(degree, offsets, logsum, N);
    fill_kernel<<<(E + 255) / 256, 256, 0, stream>>>(ei, offsets, csr_src, E);
    agg_kernel<<<(Mpad * 64 + 255) / 256, 256, 0, stream>>>(x, csr_src, offsets, degree, logsum,
                                                            Zhi, Zlo, ampv, attv, N, Mpad);
    wbuild_kernel<<<(NGEMM * KDIM + 255) / 256, 256, 0, stream>>>(Wmsg, Wroot, Whi, Wlo);
    dim3 ggrid(Mb, 2);
    gemm_kernel<<<ggrid, 1024, 0, stream>>>(Zhi, Zlo, Whi, Wlo, ampv, attv, bmsg, broot, out, N);
}

// Round 8
// 398.118 us; speedup vs baseline: 1.9606x; 1.9606x over previous
//
#include <hip/hip_runtime.h>
#include <cmath>

#define IN_CH 128
#define OUT_CH 128
#define KDIM 512           // Z row: x(128) | sum(128) | mean(128) | max(128)
#define NGEMM 384          // W^T rows: permuted (colgroup, wavehalf, section, ocol16)
#define GBM 256            // gemm rows per block
#define GBN 192            // gemm cols (W^T rows) per block

typedef __attribute__((ext_vector_type(8))) short bfrag;   // 8 bf16 in 4 VGPRs
typedef __attribute__((ext_vector_type(4))) float f32x4;

// float -> bf16 round-to-nearest-even (bit pattern)
__device__ __forceinline__ unsigned short f2bf(float f) {
    unsigned int u = __float_as_uint(f);
    return (unsigned short)((u + 0x7FFFu + ((u >> 16) & 1u)) >> 16);
}
__device__ __forceinline__ float bf2f(unsigned short h) {
    return __uint_as_float(((unsigned int)h) << 16);
}

// async 16B global->LDS (wave-level; LDS side is lane-linear base+lane*16)
__device__ __forceinline__ void gl2lds16(const void* g, void* l) {
    __builtin_amdgcn_global_load_lds(
        (const __attribute__((address_space(1))) unsigned int*)g,
        (__attribute__((address_space(3))) unsigned int*)l, 16, 0, 0);
}

// ---------------- CSR build ----------------

__global__ void degree_kernel(const int* __restrict__ ei, int* __restrict__ degree, int E) {
    int e = blockIdx.x * blockDim.x + threadIdx.x;
    if (e < E) atomicAdd(&degree[ei[E + e]], 1);
}

__global__ __launch_bounds__(1024) void scan_kernel(const int* __restrict__ degree,
                                                    int* __restrict__ offsets,
                                                    float* __restrict__ logsum, int n) {
    const int T = 1024;
    int tid = threadIdx.x;
    int chunk = (n + T - 1) / T;
    int beg = min(tid * chunk, n);
    int end = min(beg + chunk, n);
    int s = 0;
    float ls = 0.f;
    for (int i = beg; i < end; ++i) {
        int d = degree[i];
        s += d;
        ls += logf((float)d + 2.0f);   // == log1p(d+1)
    }
    __shared__ int part[T];
    __shared__ float fl[T];
    part[tid] = s;
    fl[tid] = ls;
    __syncthreads();
    for (int off = 1; off < T; off <<= 1) {
        int v = (tid >= off) ? part[tid - off] : 0;
        __syncthreads();
        part[tid] += v;
        __syncthreads();
    }
    for (int off = T / 2; off > 0; off >>= 1) {
        if (tid < off) fl[tid] += fl[tid + off];
        __syncthreads();
    }
    if (tid == 0) logsum[0] = fl[0];
    int prefix = (tid == 0) ? 0 : part[tid - 1];
    for (int i = beg; i < end; ++i) {
        offsets[i] = prefix;
        prefix += degree[i];
    }
    if (tid == T - 1) offsets[n] = prefix;
}

// fill bumps offsets[] in place; afterwards offsets[v] == end of v's segment.
// agg recovers beg = end - degree[v]. (No cursor array, no extra memset.)
__global__ void fill_kernel(const int* __restrict__ ei, int* __restrict__ offsets,
                            int* __restrict__ csr_src, int E) {
    int e = blockIdx.x * blockDim.x + threadIdx.x;
    if (e < E) {
        int src = ei[e];
        int dst = ei[E + e];
        int pos = atomicAdd(&offsets[dst], 1);
        csr_src[pos] = src;
    }
}

// ---------------- Aggregation: one WAVE per node, EDGE-PAIR float4 gathers ---------

__global__ __launch_bounds__(256) void agg_kernel(const float* __restrict__ x,
                                                  const int* __restrict__ csr_src,
                                                  const int* __restrict__ offsets,
                                                  const int* __restrict__ degree,
                                                  const float* __restrict__ logsum,
                                                  unsigned short* __restrict__ Zhi,
                                                  unsigned short* __restrict__ Zlo,
                                                  float* __restrict__ ampv,
                                                  float* __restrict__ attv,
                                                  int N, int Mpad) {
    int node = (blockIdx.x * 256 + threadIdx.x) >> 6;
    int lane = threadIdx.x & 63;
    if (node >= Mpad) return;
    int h = lane >> 5;
    int c4 = lane & 31;
    long zbase = (long)node * KDIM + c4 * 4;
    if (node >= N) {   // pad rows: zero so GEMM reads are harmless
        if (h == 0) {
            uint2 z = make_uint2(0u, 0u);
            #pragma unroll
            for (int sec = 0; sec < 4; ++sec) {
                *(uint2*)&Zhi[zbase + sec * 128] = z;
                *(uint2*)&Zlo[zbase + sec * 128] = z;
            }
        }
        return;
    }
    int deg = degree[node];
    int end = offsets[node];          // post-fill end of segment
    int beg = end - deg;
    const float NEG = -3.402823466e38f;
    float4 s[4], m[4];
    #pragma unroll
    for (int u = 0; u < 4; ++u) {
        s[u] = make_float4(0.f, 0.f, 0.f, 0.f);
        m[u] = make_float4(NEG, NEG, NEG, NEG);
    }
    int i = beg;
    for (; i + 8 <= end; i += 8) {      // 4 pair-slots = 8 edges, 4 indep chains
        int idx[4];
        #pragma unroll
        for (int u = 0; u < 4; ++u) idx[u] = csr_src[i + u * 2 + h];
        float4 v[4];
        #pragma unroll
        for (int u = 0; u < 4; ++u) v[u] = *(const float4*)&x[(long)idx[u] * IN_CH + c4 * 4];
        #pragma unroll
        for (int u = 0; u < 4; ++u) {
            s[u].x += v[u].x; s[u].y += v[u].y; s[u].z += v[u].z; s[u].w += v[u].w;
            m[u].x = fmaxf(m[u].x, v[u].x); m[u].y = fmaxf(m[u].y, v[u].y);
            m[u].z = fmaxf(m[u].z, v[u].z); m[u].w = fmaxf(m[u].w, v[u].w);
        }
    }
    for (; i < end; i += 2) {           // tail pairs (upper half may be inactive)
        int e = i + h;
        if (e < end) {
            int idx = csr_src[e];
            float4 v = *(const float4*)&x[(long)idx * IN_CH + c4 * 4];
            s[0].x += v.x; s[0].y += v.y; s[0].z += v.z; s[0].w += v.w;
            m[0].x = fmaxf(m[0].x, v.x); m[0].y = fmaxf(m[0].y, v.y);
            m[0].z = fmaxf(m[0].z, v.z); m[0].w = fmaxf(m[0].w, v.w);
        }
    }
    float4 sum, mx;
    sum.x = (s[0].x + s[1].x) + (s[2].x + s[3].x);
    sum.y = (s[0].y + s[1].y) + (s[2].y + s[3].y);
    sum.z = (s[0].z + s[1].z) + (s[2].z + s[3].z);
    sum.w = (s[0].w + s[1].w) + (s[2].w + s[3].w);
    mx.x = fmaxf(fmaxf(m[0].x, m[1].x), fmaxf(m[2].x, m[3].x));
    mx.y = fmaxf(fmaxf(m[0].y, m[1].y), fmaxf(m[2].y, m[3].y));
    mx.z = fmaxf(fmaxf(m[0].z, m[1].z), fmaxf(m[2].z, m[3].z));
    mx.w = fmaxf(fmaxf(m[0].w, m[1].w), fmaxf(m[2].w, m[3].w));
    // cross-half combine
    sum.x += __shfl_xor(sum.x, 32); sum.y += __shfl_xor(sum.y, 32);
    sum.z += __shfl_xor(sum.z, 32); sum.w += __shfl_xor(sum.w, 32);
    mx.x = fmaxf(mx.x, __shfl_xor(mx.x, 32)); mx.y = fmaxf(mx.y, __shfl_xor(mx.y, 32));
    mx.z = fmaxf(mx.z, __shfl_xor(mx.z, 32)); mx.w = fmaxf(mx.w, __shfl_xor(mx.w, 32));

    float inv = 1.0f / fmaxf((float)deg, 1.0f);
    float4 mean = make_float4(sum.x * inv, sum.y * inv, sum.z * inv, sum.w * inv);
    if (deg == 0) mx = make_float4(0.f, 0.f, 0.f, 0.f);
    float4 xv = *(const float4*)&x[(long)node * IN_CH + c4 * 4];

    if (h == 0) {
        float4 secs[4] = { xv, sum, mean, mx };
        #pragma unroll
        for (int sec = 0; sec < 4; ++sec) {
            float4 v = secs[sec];
            unsigned short hx = f2bf(v.x), hy = f2bf(v.y), hz = f2bf(v.z), hw = f2bf(v.w);
            uint2 hi = make_uint2((unsigned)hx | ((unsigned)hy << 16),
                                  (unsigned)hz | ((unsigned)hw << 16));
            uint2 lo = make_uint2((unsigned)f2bf(v.x - bf2f(hx)) | ((unsigned)f2bf(v.y - bf2f(hy)) << 16),
                                  (unsigned)f2bf(v.z - bf2f(hz)) | ((unsigned)f2bf(v.w - bf2f(hw)) << 16));
            *(uint2*)&Zhi[zbase + sec * 128] = hi;
            *(uint2*)&Zlo[zbase + sec * 128] = lo;
        }
    }
    if (lane == 0) {
        float ref = fmaxf(logsum[0] / (float)N, 1.0f);
        float dt = log1pf((float)deg + 1.0f);
        ampv[node] = dt / ref;
        attv[node] = ref / fmaxf(dt, 1e-6f);
    }
}

// ---------------- Weight build: permuted row-major W^T, bf16 hi/lo -----------------
// jp = cg*96 + s16*16 + r16, s16 in [0,6): wn2 = s16/3, sec = s16%3,
// ocol = cg*32 + wn2*16 + r16.

__global__ void wbuild_kernel(const float* __restrict__ Wmsg, const float* __restrict__ Wroot,
                              unsigned short* __restrict__ Whi, unsigned short* __restrict__ Wlo) {
    int idx = blockIdx.x * 256 + threadIdx.x;
    if (idx >= NGEMM * KDIM) return;
    int jp = idx >> 9;       // 0..383
    int k = idx & 511;
    int cg = jp / 96;
    int rem = jp - cg * 96;
    int s16 = rem >> 4;
    int r16 = rem & 15;
    int wn2 = s16 / 3;
    int sec = s16 - wn2 * 3;
    int ocol = cg * 32 + wn2 * 16 + r16;
    float v;
    if (k < 128) {
        v = (sec == 0) ? Wroot[ocol * 128 + k] : 0.f;
    } else {
        int a = (k - 128) >> 7;
        int c = (k - 128) & 127;
        v = Wmsg[ocol * 1152 + (a * 3 + sec) * 128 + c];
    }
    unsigned short h = f2bf(v);
    Whi[idx] = h;
    Wlo[idx] = f2bf(v - bf2f(h));
}

// ---------------- MFMA GEMM: minimize staged bytes ---------------------------------
// Staging model (measured r6): time = staged_bytes / ~6.8 TB/s device-wide.
// BM=256, BN=192, BK=32: staged = 205MB (A hi+lo) + 154MB (B hi+lo) = 359 MB -> ~53us.
// 1024 thr = 16 waves; wave tile 64 rows x 48 cols (4x3 tiles), acc = 48 AGPR.
// __launch_bounds__(1024, 4): 128-reg budget (r7's (.,8) capped at 64 -> acc SPILLED
// to scratch: WRITE_SIZE 1.16GB, 524us. 2nd arg is waves/EU!).
// Inner loop B-first grouping keeps peak live frags at 6B+2A = 32 regs + 48 acc.
// LDS 56 KB single-buffer: Ahi[0,8192) Alo[8192,16384) Bhi[16384,22528) Blo[22528,28672).

__global__ __launch_bounds__(1024, 4) void gemm_kernel(const unsigned short* __restrict__ Zhi,
                                                       const unsigned short* __restrict__ Zlo,
                                                       const unsigned short* __restrict__ Whi,
                                                       const unsigned short* __restrict__ Wlo,
                                                       const float* __restrict__ ampv,
                                                       const float* __restrict__ attv,
                                                       const float* __restrict__ bmsg,
                                                       const float* __restrict__ broot,
                                                       float* __restrict__ out, int M) {
    __shared__ unsigned short lds[28672];   // 56 KB
    const int tid = threadIdx.x;
    const int w = tid >> 6;                 // 0..15
    const int lane = tid & 63;
    const int r16 = lane & 15, q = lane >> 4;
    const int wm = w >> 2, wn = w & 3;
    const int row0 = blockIdx.x * GBM;
    const int cg2 = blockIdx.y;             // 0..1

    // staging sources (ushort units); chunk c = l*1024 + tid, LDS dst = c*16 B
    const unsigned short* sAh = Zhi + (long)(row0 + w * 16 + r16) * KDIM + q * 8;
    const unsigned short* sAl = Zlo + (long)(row0 + w * 16 + r16) * KDIM + q * 8;
    const unsigned short* sB2 = (w < 12)
        ? Whi + (long)(cg2 * GBN + w * 16 + r16) * KDIM + q * 8
        : Wlo + (long)(cg2 * GBN + (w - 12) * 16 + r16) * KDIM + q * 8;
    const unsigned short* sB3 = Wlo + (long)(cg2 * GBN + (4 + w) * 16 + r16) * KDIM + q * 8;
    char* ldsb = (char*)lds;
    const int d0 = tid * 16, d1 = (1024 + tid) * 16, d2 = (2048 + tid) * 16, d3 = (3072 + tid) * 16;

    f32x4 acc[4][3] = {};
    const int jtb = (wn >> 1) * 6 + (wn & 1) * 3;

    #pragma unroll 1
    for (int it = 0; it < 16; ++it) {
        if (it) __syncthreads();            // WAR: prior iter's ds_reads done
        gl2lds16(sAh, ldsb + d0);
        gl2lds16(sAl, ldsb + d1);
        gl2lds16(sB2, ldsb + d2);
        if (w < 8) gl2lds16(sB3, ldsb + d3);
        sAh += 32; sAl += 32; sB2 += 32; sB3 += 32;
        __syncthreads();                    // staging visible

        // B fragments first (6 frags live = 24 regs), then per-mt A pair (8 regs)
        bfrag bh[3], bl[3];
        #pragma unroll
        for (int nt = 0; nt < 3; ++nt) {
            int chb = ((jtb + nt) * 64 + lane) * 8;
            bh[nt] = *(const bfrag*)&lds[16384 + chb];
            bl[nt] = *(const bfrag*)&lds[22528 + chb];
        }
        #pragma unroll
        for (int mt = 0; mt < 4; ++mt) {
            int ch = ((wm * 4 + mt) * 64 + lane) * 8;
            bfrag ah = *(const bfrag*)&lds[ch];
            bfrag al = *(const bfrag*)&lds[8192 + ch];
            #pragma unroll
            for (int nt = 0; nt < 3; ++nt) {
                acc[mt][nt] = __builtin_amdgcn_mfma_f32_16x16x32_bf16(ah, bh[nt], acc[mt][nt], 0, 0, 0);
                acc[mt][nt] = __builtin_amdgcn_mfma_f32_16x16x32_bf16(ah, bl[nt], acc[mt][nt], 0, 0, 0);
                acc[mt][nt] = __builtin_amdgcn_mfma_f32_16x16x32_bf16(al, bh[nt], acc[mt][nt], 0, 0, 0);
            }
        }
    }

    // fused epilogue: C/D layout col=lane&15, row=q*4+r (verified m89/m91)
    const int col = (cg2 * 2 + (wn >> 1)) * 32 + (wn & 1) * 16 + r16;
    const float bias = bmsg[col] + broot[col];
    #pragma unroll
    for (int mt = 0; mt < 4; ++mt) {
        #pragma unroll
        for (int r = 0; r < 4; ++r) {
            int row = row0 + wm * 64 + mt * 16 + q * 4 + r;
            if (row < M) {
                float v = acc[mt][0][r]
                        + ampv[row] * acc[mt][1][r]
                        + attv[row] * acc[mt][2][r] + bias;
                out[(long)row * OUT_CH + col] = v;
            }
        }
    }
}

// ---------------- Launch ----------------

extern "C" void kernel_launch(void* const* d_in, const int* in_sizes, int n_in,
                              void* d_out, int out_size, void* d_ws, size_t ws_size,
                              hipStream_t stream) {
    const float* x     = (const float*)d_in[0];
    const int*   ei    = (const int*)d_in[1];
    const float* Wmsg  = (const float*)d_in[2];
    const float* bmsg  = (const float*)d_in[3];
    const float* Wroot = (const float*)d_in[4];
    const float* broot = (const float*)d_in[5];
    float* out = (float*)d_out;

    int N = in_sizes[0] / IN_CH;           // 50000
    int E = in_sizes[1] / 2;               // 600000
    int Mb = (N + GBM - 1) / GBM;          // 196
    int Mpad = Mb * GBM;                   // 50176

    char* ws = (char*)d_ws;
    size_t off = 0;
    auto alloc = [&](size_t bytes) -> void* {
        void* p = ws + off;
        off = (off + bytes + 255) & ~(size_t)255;
        return p;
    };
    int* degree  = (int*)alloc((size_t)N * 4);
    int* offsets = (int*)alloc((size_t)(N + 1) * 4);
    float* logsum = (float*)alloc(4);
    int* csr_src = (int*)alloc((size_t)E * 4);
    unsigned short* Whi = (unsigned short*)alloc((size_t)NGEMM * KDIM * 2);
    unsigned short* Wlo = (unsigned short*)alloc((size_t)NGEMM * KDIM * 2);
    unsigned short* Zhi = (unsigned short*)alloc((size_t)Mpad * KDIM * 2);
    unsigned short* Zlo = (unsigned short*)alloc((size_t)Mpad * KDIM * 2);
    float* ampv = (float*)alloc((size_t)N * 4);
    float* attv = (float*)alloc((size_t)N * 4);

    hipMemsetAsync(degree, 0, (size_t)N * 4, stream);

    degree_kernel<<<(E + 255) / 256, 256, 0, stream>>>(ei, degree, E);
    scan_kernel<<<1, 1024, 0, stream>>>(degree, offsets, logsum, N);
    fill_kernel<<<(E + 255) / 256, 256, 0, stream>>>(ei, offsets, csr_src, E);
    agg_kernel<<<(Mpad * 64 + 255) / 256, 256, 0, stream>>>(x, csr_src, offsets, degree, logsum,
                                                            Zhi, Zlo, ampv, attv, N, Mpad);
    wbuild_kernel<<<(NGEMM * KDIM + 255) / 256, 256, 0, stream>>>(Wmsg, Wroot, Whi, Wlo);
    dim3 ggrid(Mb, 2);
    gemm_kernel<<<ggrid, 1024, 0, stream>>>(Zhi, Zlo, Whi, Wlo, ampv, attv, bmsg, broot, out, N);
}

// Round 9
// 380.873 us; speedup vs baseline: 2.0494x; 1.0453x over previous
//
#include <hip/hip_runtime.h>
#include <cmath>

#define IN_CH 128
#define OUT_CH 128
#define KDIM 512           // Z row: x(128) | sum(128) | mean(128) | max(128)
#define NGEMM 384          // W^T rows: permuted (colgroup, wavehalf, section, ocol16)
#define GBM 256            // gemm rows per block
#define GBN 192            // gemm cols (W^T rows) per block
#define PIPE_LDS_BYTES (114688 + 16)   // 2 x 56KB ring + 4 flag ints

typedef __attribute__((ext_vector_type(8))) short bfrag;   // 8 bf16 in 4 VGPRs
typedef __attribute__((ext_vector_type(4))) float f32x4;

// float -> bf16 round-to-nearest-even (bit pattern)
__device__ __forceinline__ unsigned short f2bf(float f) {
    unsigned int u = __float_as_uint(f);
    return (unsigned short)((u + 0x7FFFu + ((u >> 16) & 1u)) >> 16);
}
__device__ __forceinline__ float bf2f(unsigned short h) {
    return __uint_as_float(((unsigned int)h) << 16);
}

// async 16B global->LDS (wave-level; LDS side is lane-linear base+lane*16)
__device__ __forceinline__ void gl2lds16(const void* g, void* l) {
    __builtin_amdgcn_global_load_lds(
        (const __attribute__((address_space(1))) unsigned int*)g,
        (__attribute__((address_space(3))) unsigned int*)l, 16, 0, 0);
}

// ---------------- CSR build ----------------

__global__ void degree_kernel(const int* __restrict__ ei, int* __restrict__ degree, int E) {
    int e = blockIdx.x * blockDim.x + threadIdx.x;
    if (e < E) atomicAdd(&degree[ei[E + e]], 1);
}

__global__ __launch_bounds__(1024) void scan_kernel(const int* __restrict__ degree,
                                                    int* __restrict__ offsets,
                                                    float* __restrict__ logsum, int n) {
    const int T = 1024;
    int tid = threadIdx.x;
    int chunk = (n + T - 1) / T;
    int beg = min(tid * chunk, n);
    int end = min(beg + chunk, n);
    int s = 0;
    float ls = 0.f;
    for (int i = beg; i < end; ++i) {
        int d = degree[i];
        s += d;
        ls += logf((float)d + 2.0f);   // == log1p(d+1)
    }
    __shared__ int part[T];
    __shared__ float fl[T];
    part[tid] = s;
    fl[tid] = ls;
    __syncthreads();
    for (int off = 1; off < T; off <<= 1) {
        int v = (tid >= off) ? part[tid - off] : 0;
        __syncthreads();
        part[tid] += v;
        __syncthreads();
    }
    for (int off = T / 2; off > 0; off >>= 1) {
        if (tid < off) fl[tid] += fl[tid + off];
        __syncthreads();
    }
    if (tid == 0) logsum[0] = fl[0];
    int prefix = (tid == 0) ? 0 : part[tid - 1];
    for (int i = beg; i < end; ++i) {
        offsets[i] = prefix;
        prefix += degree[i];
    }
    if (tid == T - 1) offsets[n] = prefix;
}

// fill bumps offsets[] in place; afterwards offsets[v] == end of v's segment.
__global__ void fill_kernel(const int* __restrict__ ei, int* __restrict__ offsets,
                            int* __restrict__ csr_src, int E) {
    int e = blockIdx.x * blockDim.x + threadIdx.x;
    if (e < E) {
        int src = ei[e];
        int dst = ei[E + e];
        int pos = atomicAdd(&offsets[dst], 1);
        csr_src[pos] = src;
    }
}

// ---------------- Aggregation: one WAVE per node, EDGE-PAIR float4 gathers ---------

__global__ __launch_bounds__(256) void agg_kernel(const float* __restrict__ x,
                                                  const int* __restrict__ csr_src,
                                                  const int* __restrict__ offsets,
                                                  const int* __restrict__ degree,
                                                  const float* __restrict__ logsum,
                                                  unsigned short* __restrict__ Zhi,
                                                  unsigned short* __restrict__ Zlo,
                                                  float* __restrict__ ampv,
                                                  float* __restrict__ attv,
                                                  int N, int Mpad) {
    int node = (blockIdx.x * 256 + threadIdx.x) >> 6;
    int lane = threadIdx.x & 63;
    if (node >= Mpad) return;
    int h = lane >> 5;
    int c4 = lane & 31;
    long zbase = (long)node * KDIM + c4 * 4;
    if (node >= N) {   // pad rows: zero so GEMM reads are harmless
        if (h == 0) {
            uint2 z = make_uint2(0u, 0u);
            #pragma unroll
            for (int sec = 0; sec < 4; ++sec) {
                *(uint2*)&Zhi[zbase + sec * 128] = z;
                *(uint2*)&Zlo[zbase + sec * 128] = z;
            }
        }
        return;
    }
    int deg = degree[node];
    int end = offsets[node];          // post-fill end of segment
    int beg = end - deg;
    const float NEG = -3.402823466e38f;
    float4 s[4], m[4];
    #pragma unroll
    for (int u = 0; u < 4; ++u) {
        s[u] = make_float4(0.f, 0.f, 0.f, 0.f);
        m[u] = make_float4(NEG, NEG, NEG, NEG);
    }
    int i = beg;
    for (; i + 8 <= end; i += 8) {      // 4 pair-slots = 8 edges, 4 indep chains
        int idx[4];
        #pragma unroll
        for (int u = 0; u < 4; ++u) idx[u] = csr_src[i + u * 2 + h];
        float4 v[4];
        #pragma unroll
        for (int u = 0; u < 4; ++u) v[u] = *(const float4*)&x[(long)idx[u] * IN_CH + c4 * 4];
        #pragma unroll
        for (int u = 0; u < 4; ++u) {
            s[u].x += v[u].x; s[u].y += v[u].y; s[u].z += v[u].z; s[u].w += v[u].w;
            m[u].x = fmaxf(m[u].x, v[u].x); m[u].y = fmaxf(m[u].y, v[u].y);
            m[u].z = fmaxf(m[u].z, v[u].z); m[u].w = fmaxf(m[u].w, v[u].w);
        }
    }
    for (; i < end; i += 2) {           // tail pairs (upper half may be inactive)
        int e = i + h;
        if (e < end) {
            int idx = csr_src[e];
            float4 v = *(const float4*)&x[(long)idx * IN_CH + c4 * 4];
            s[0].x += v.x; s[0].y += v.y; s[0].z += v.z; s[0].w += v.w;
            m[0].x = fmaxf(m[0].x, v.x); m[0].y = fmaxf(m[0].y, v.y);
            m[0].z = fmaxf(m[0].z, v.z); m[0].w = fmaxf(m[0].w, v.w);
        }
    }
    float4 sum, mx;
    sum.x = (s[0].x + s[1].x) + (s[2].x + s[3].x);
    sum.y = (s[0].y + s[1].y) + (s[2].y + s[3].y);
    sum.z = (s[0].z + s[1].z) + (s[2].z + s[3].z);
    sum.w = (s[0].w + s[1].w) + (s[2].w + s[3].w);
    mx.x = fmaxf(fmaxf(m[0].x, m[1].x), fmaxf(m[2].x, m[3].x));
    mx.y = fmaxf(fmaxf(m[0].y, m[1].y), fmaxf(m[2].y, m[3].y));
    mx.z = fmaxf(fmaxf(m[0].z, m[1].z), fmaxf(m[2].z, m[3].z));
    mx.w = fmaxf(fmaxf(m[0].w, m[1].w), fmaxf(m[2].w, m[3].w));
    // cross-half combine
    sum.x += __shfl_xor(sum.x, 32); sum.y += __shfl_xor(sum.y, 32);
    sum.z += __shfl_xor(sum.z, 32); sum.w += __shfl_xor(sum.w, 32);
    mx.x = fmaxf(mx.x, __shfl_xor(mx.x, 32)); mx.y = fmaxf(mx.y, __shfl_xor(mx.y, 32));
    mx.z = fmaxf(mx.z, __shfl_xor(mx.z, 32)); mx.w = fmaxf(mx.w, __shfl_xor(mx.w, 32));

    float inv = 1.0f / fmaxf((float)deg, 1.0f);
    float4 mean = make_float4(sum.x * inv, sum.y * inv, sum.z * inv, sum.w * inv);
    if (deg == 0) mx = make_float4(0.f, 0.f, 0.f, 0.f);
    float4 xv = *(const float4*)&x[(long)node * IN_CH + c4 * 4];

    if (h == 0) {
        float4 secs[4] = { xv, sum, mean, mx };
        #pragma unroll
        for (int sec = 0; sec < 4; ++sec) {
            float4 v = secs[sec];
            unsigned short hx = f2bf(v.x), hy = f2bf(v.y), hz = f2bf(v.z), hw = f2bf(v.w);
            uint2 hi = make_uint2((unsigned)hx | ((unsigned)hy << 16),
                                  (unsigned)hz | ((unsigned)hw << 16));
            uint2 lo = make_uint2((unsigned)f2bf(v.x - bf2f(hx)) | ((unsigned)f2bf(v.y - bf2f(hy)) << 16),
                                  (unsigned)f2bf(v.z - bf2f(hz)) | ((unsigned)f2bf(v.w - bf2f(hw)) << 16));
            *(uint2*)&Zhi[zbase + sec * 128] = hi;
            *(uint2*)&Zlo[zbase + sec * 128] = lo;
        }
    }
    if (lane == 0) {
        float ref = fmaxf(logsum[0] / (float)N, 1.0f);
        float dt = log1pf((float)deg + 1.0f);
        ampv[node] = dt / ref;
        attv[node] = ref / fmaxf(dt, 1e-6f);
    }
}

// ---------------- Weight build: permuted row-major W^T, bf16 hi/lo -----------------

__global__ void wbuild_kernel(const float* __restrict__ Wmsg, const float* __restrict__ Wroot,
                              unsigned short* __restrict__ Whi, unsigned short* __restrict__ Wlo) {
    int idx = blockIdx.x * 256 + threadIdx.x;
    if (idx >= NGEMM * KDIM) return;
    int jp = idx >> 9;       // 0..383
    int k = idx & 511;
    int cg = jp / 96;
    int rem = jp - cg * 96;
    int s16 = rem >> 4;
    int r16 = rem & 15;
    int wn2 = s16 / 3;
    int sec = s16 - wn2 * 3;
    int ocol = cg * 32 + wn2 * 16 + r16;
    float v;
    if (k < 128) {
        v = (sec == 0) ? Wroot[ocol * 128 + k] : 0.f;
    } else {
        int a = (k - 128) >> 7;
        int c = (k - 128) & 127;
        v = Wmsg[ocol * 1152 + (a * 3 + sec) * 128 + c];
    }
    unsigned short h = f2bf(v);
    Whi[idx] = h;
    Wlo[idx] = f2bf(v - bf2f(h));
}

// ---------------- MFMA GEMM, PIPELINED: barrier-free spin-flag 2-deep LDS ring -----
// r8 post-mortem: single-buffer serializes stage(33.7us) + MFMA(15.5us) per block,
// 1 block/CU -> 3.1 TB/s effective vs ~6.8 path ceiling. Barriers force vmcnt(0)
// drains of prefetches (m97 plateau), so: NO barriers. Per wave, iter i (buf b=i&1):
//   1. s_waitcnt vmcnt(0)        -- own stage(i) landed (stage(i+1) not yet issued)
//   2. ready[b]++ (lane 0)
//   3. WAR-spin done[b^1] >= 16*((i+1)>>1), then FIRE stage(i+1) (not waited)
//   4. spin ready[b] >= 16*((i>>1)+1)   -- all waves' stage(i) landed
//   5. ds_read frags + 36 MFMA   -- overlaps stage(i+1) in flight
//   6. done[b]++ (lane 0)
// Every wait references strictly-earlier work in every wave's program order -> no
// deadlock. Ring = 112 KB (dynamic LDS, > 64 KB static cap) + 4 flag ints.

__global__ __launch_bounds__(1024, 4) void gemm_pipe(const unsigned short* __restrict__ Zhi,
                                                     const unsigned short* __restrict__ Zlo,
                                                     const unsigned short* __restrict__ Whi,
                                                     const unsigned short* __restrict__ Wlo,
                                                     const float* __restrict__ ampv,
                                                     const float* __restrict__ attv,
                                                     const float* __restrict__ bmsg,
                                                     const float* __restrict__ broot,
                                                     float* __restrict__ out, int M) {
    extern __shared__ char smem[];
    unsigned short* lds = (unsigned short*)smem;
    int* flags = (int*)(smem + 114688);     // [ready0, ready1, done0, done1]
    volatile int* vflags = (volatile int*)flags;
    const int tid = threadIdx.x;
    const int w = tid >> 6;                 // 0..15
    const int lane = tid & 63;
    const int r16 = lane & 15, q = lane >> 4;
    const int wm = w >> 2, wn = w & 3;
    const int row0 = blockIdx.x * GBM;
    const int cg2 = blockIdx.y;             // 0..1

    if (tid == 0) { flags[0] = 0; flags[1] = 0; flags[2] = 0; flags[3] = 0; }
    __syncthreads();                        // only barrier; nothing in flight yet

    // staging sources (identical geometry to r8); advance 32 ushorts per iter
    const unsigned short* sAh = Zhi + (long)(row0 + w * 16 + r16) * KDIM + q * 8;
    const unsigned short* sAl = Zlo + (long)(row0 + w * 16 + r16) * KDIM + q * 8;
    const unsigned short* sB2 = (w < 12)
        ? Whi + (long)(cg2 * GBN + w * 16 + r16) * KDIM + q * 8
        : Wlo + (long)(cg2 * GBN + (w - 12) * 16 + r16) * KDIM + q * 8;
    const unsigned short* sB3 = Wlo + (long)(cg2 * GBN + (4 + w) * 16 + r16) * KDIM + q * 8;
    char* ldsb = smem;
    const int d0 = tid * 16, d1 = (1024 + tid) * 16, d2 = (2048 + tid) * 16, d3 = (3072 + tid) * 16;

    // prologue: stage iter 0 into buf 0
    gl2lds16(sAh, ldsb + d0);
    gl2lds16(sAl, ldsb + d1);
    gl2lds16(sB2, ldsb + d2);
    if (w < 8) gl2lds16(sB3, ldsb + d3);
    sAh += 32; sAl += 32; sB2 += 32; sB3 += 32;

    f32x4 acc[4][3] = {};
    const int jtb = (wn >> 1) * 6 + (wn & 1) * 3;

    for (int it = 0; it < 16; ++it) {
        const int b = it & 1;
        __builtin_amdgcn_s_waitcnt(0x0F70);             // vmcnt(0), lgkm/exp unconstrained
        if (lane == 0) atomicAdd(&flags[b], 1);          // ready[b]++
        if (it + 1 < 16) {
            const int nb = b ^ 1;
            const int needd = 16 * ((it + 1) >> 1);      // prior uses of buf nb consumed
            if (needd) { while (vflags[2 + nb] < needd) {} }
            const int boff = nb * 57344;
            gl2lds16(sAh, ldsb + boff + d0);             // fire-and-forget prefetch
            gl2lds16(sAl, ldsb + boff + d1);
            gl2lds16(sB2, ldsb + boff + d2);
            if (w < 8) gl2lds16(sB3, ldsb + boff + d3);
            sAh += 32; sAl += 32; sB2 += 32; sB3 += 32;
        }
        const int needr = 16 * ((it >> 1) + 1);
        while (vflags[b] < needr) {}                     // all 16 waves staged buf b
        const int rb = b * 28672;                        // ring offset, ushort units

        bfrag bh[3], bl[3];
        #pragma unroll
        for (int nt = 0; nt < 3; ++nt) {
            int chb = ((jtb + nt) * 64 + lane) * 8;
            bh[nt] = *(const bfrag*)&lds[rb + 16384 + chb];
            bl[nt] = *(const bfrag*)&lds[rb + 22528 + chb];
        }
        #pragma unroll
        for (int mt = 0; mt < 4; ++mt) {
            int ch = ((wm * 4 + mt) * 64 + lane) * 8;
            bfrag ah = *(const bfrag*)&lds[rb + ch];
            bfrag al = *(const bfrag*)&lds[rb + 8192 + ch];
            #pragma unroll
            for (int nt = 0; nt < 3; ++nt) {
                acc[mt][nt] = __builtin_amdgcn_mfma_f32_16x16x32_bf16(ah, bh[nt], acc[mt][nt], 0, 0, 0);
                acc[mt][nt] = __builtin_amdgcn_mfma_f32_16x16x32_bf16(ah, bl[nt], acc[mt][nt], 0, 0, 0);
                acc[mt][nt] = __builtin_amdgcn_mfma_f32_16x16x32_bf16(al, bh[nt], acc[mt][nt], 0, 0, 0);
            }
        }
        if (lane == 0) atomicAdd(&flags[2 + b], 1);      // done[b]++
    }

    // fused epilogue: C/D layout col=lane&15, row=q*4+r (verified m89/m91)
    const int col = (cg2 * 2 + (wn >> 1)) * 32 + (wn & 1) * 16 + r16;
    const float bias = bmsg[col] + broot[col];
    #pragma unroll
    for (int mt = 0; mt < 4; ++mt) {
        #pragma unroll
        for (int r = 0; r < 4; ++r) {
            int row = row0 + wm * 64 + mt * 16 + q * 4 + r;
            if (row < M) {
                float v = acc[mt][0][r]
                        + ampv[row] * acc[mt][1][r]
                        + attv[row] * acc[mt][2][r] + bias;
                out[(long)row * OUT_CH + col] = v;
            }
        }
    }
}

// ---------------- fallback: r8 single-buffer GEMM (static 56 KB), unchanged --------

__global__ __launch_bounds__(1024, 4) void gemm_sb(const unsigned short* __restrict__ Zhi,
                                                   const unsigned short* __restrict__ Zlo,
                                                   const unsigned short* __restrict__ Whi,
                                                   const unsigned short* __restrict__ Wlo,
                                                   const float* __restrict__ ampv,
                                                   const float* __restrict__ attv,
                                                   const float* __restrict__ bmsg,
                                                   const float* __restrict__ broot,
                                                   float* __restrict__ out, int M) {
    __shared__ unsigned short lds[28672];   // 56 KB
    const int tid = threadIdx.x;
    const int w = tid >> 6;
    const int lane = tid & 63;
    const int r16 = lane & 15, q = lane >> 4;
    const int wm = w >> 2, wn = w & 3;
    const int row0 = blockIdx.x * GBM;
    const int cg2 = blockIdx.y;

    const unsigned short* sAh = Zhi + (long)(row0 + w * 16 + r16) * KDIM + q * 8;
    const unsigned short* sAl = Zlo + (long)(row0 + w * 16 + r16) * KDIM + q * 8;
    const unsigned short* sB2 = (w < 12)
        ? Whi + (long)(cg2 * GBN + w * 16 + r16) * KDIM + q * 8
        : Wlo + (long)(cg2 * GBN + (w - 12) * 16 + r16) * KDIM + q * 8;
    const unsigned short* sB3 = Wlo + (long)(cg2 * GBN + (4 + w) * 16 + r16) * KDIM + q * 8;
    char* ldsb = (char*)lds;
    const int d0 = tid * 16, d1 = (1024 + tid) * 16, d2 = (2048 + tid) * 16, d3 = (3072 + tid) * 16;

    f32x4 acc[4][3] = {};
    const int jtb = (wn >> 1) * 6 + (wn & 1) * 3;

    #pragma unroll 1
    for (int it = 0; it < 16; ++it) {
        if (it) __syncthreads();
        gl2lds16(sAh, ldsb + d0);
        gl2lds16(sAl, ldsb + d1);
        gl2lds16(sB2, ldsb + d2);
        if (w < 8) gl2lds16(sB3, ldsb + d3);
        sAh += 32; sAl += 32; sB2 += 32; sB3 += 32;
        __syncthreads();

        bfrag bh[3], bl[3];
        #pragma unroll
        for (int nt = 0; nt < 3; ++nt) {
            int chb = ((jtb + nt) * 64 + lane) * 8;
            bh[nt] = *(const bfrag*)&lds[16384 + chb];
            bl[nt] = *(const bfrag*)&lds[22528 + chb];
        }
        #pragma unroll
        for (int mt = 0; mt < 4; ++mt) {
            int ch = ((wm * 4 + mt) * 64 + lane) * 8;
            bfrag ah = *(const bfrag*)&lds[ch];
            bfrag al = *(const bfrag*)&lds[8192 + ch];
            #pragma unroll
            for (int nt = 0; nt < 3; ++nt) {
                acc[mt][nt] = __builtin_amdgcn_mfma_f32_16x16x32_bf16(ah, bh[nt], acc[mt][nt], 0, 0, 0);
                acc[mt][nt] = __builtin_amdgcn_mfma_f32_16x16x32_bf16(ah, bl[nt], acc[mt][nt], 0, 0, 0);
                acc[mt][nt] = __builtin_amdgcn_mfma_f32_16x16x32_bf16(al, bh[nt], acc[mt][nt], 0, 0, 0);
            }
        }
    }

    const int col = (cg2 * 2 + (wn >> 1)) * 32 + (wn & 1) * 16 + r16;
    const float bias = bmsg[col] + broot[col];
    #pragma unroll
    for (int mt = 0; mt < 4; ++mt) {
        #pragma unroll
        for (int r = 0; r < 4; ++r) {
            int row = row0 + wm * 64 + mt * 16 + q * 4 + r;
            if (row < M) {
                float v = acc[mt][0][r]
                        + ampv[row] * acc[mt][1][r]
                        + attv[row] * acc[mt][2][r] + bias;
                out[(long)row * OUT_CH + col] = v;
            }
        }
    }
}

// ---------------- Launch ----------------

extern "C" void kernel_launch(void* const* d_in, const int* in_sizes, int n_in,
                              void* d_out, int out_size, void* d_ws, size_t ws_size,
                              hipStream_t stream) {
    const float* x     = (const float*)d_in[0];
    const int*   ei    = (const int*)d_in[1];
    const float* Wmsg  = (const float*)d_in[2];
    const float* bmsg  = (const float*)d_in[3];
    const float* Wroot = (const float*)d_in[4];
    const float* broot = (const float*)d_in[5];
    float* out = (float*)d_out;

    int N = in_sizes[0] / IN_CH;           // 50000
    int E = in_sizes[1] / 2;               // 600000
    int Mb = (N + GBM - 1) / GBM;          // 196
    int Mpad = Mb * GBM;                   // 50176

    char* ws = (char*)d_ws;
    size_t off = 0;
    auto alloc = [&](size_t bytes) -> void* {
        void* p = ws + off;
        off = (off + bytes + 255) & ~(size_t)255;
        return p;
    };
    int* degree  = (int*)alloc((size_t)N * 4);
    int* offsets = (int*)alloc((size_t)(N + 1) * 4);
    float* logsum = (float*)alloc(4);
    int* csr_src = (int*)alloc((size_t)E * 4);
    unsigned short* Whi = (unsigned short*)alloc((size_t)NGEMM * KDIM * 2);
    unsigned short* Wlo = (unsigned short*)alloc((size_t)NGEMM * KDIM * 2);
    unsigned short* Zhi = (unsigned short*)alloc((size_t)Mpad * KDIM * 2);
    unsigned short* Zlo = (unsigned short*)alloc((size_t)Mpad * KDIM * 2);
    float* ampv = (float*)alloc((size_t)N * 4);
    float* attv = (float*)alloc((size_t)N * 4);

    hipMemsetAsync(degree, 0, (size_t)N * 4, stream);

    degree_kernel<<<(E + 255) / 256, 256, 0, stream>>>(ei, degree, E);
    scan_kernel<<<1, 1024, 0, stream>>>(degree, offsets, logsum, N);
    fill_kernel<<<(E + 255) / 256, 256, 0, stream>>>(ei, offsets, csr_src, E);
    agg_kernel<<<(Mpad * 64 + 255) / 256, 256, 0, stream>>>(x, csr_src, offsets, degree, logsum,
                                                            Zhi, Zlo, ampv, attv, N, Mpad);
    wbuild_kernel<<<(NGEMM * KDIM + 255) / 256, 256, 0, stream>>>(Wmsg, Wroot, Whi, Wlo);

    // device-capability branch (same result every call; capture-safe host queries)
    bool pipe = false;
    int dev = 0;
    if (hipGetDevice(&dev) == hipSuccess) {
        int optin = 0;
        if (hipDeviceGetAttribute(&optin, hipDeviceAttributeSharedMemPerBlockOptin, dev) == hipSuccess
            && optin >= (int)PIPE_LDS_BYTES) {
            pipe = (hipFuncSetAttribute((const void*)gemm_pipe,
                                        hipFuncAttributeMaxDynamicSharedMemorySize,
                                        PIPE_LDS_BYTES) == hipSuccess);
        }
    }
    dim3 ggrid(Mb, 2);
    if (pipe) {
        gemm_pipe<<<ggrid, 1024, PIPE_LDS_BYTES, stream>>>(Zhi, Zlo, Whi, Wlo, ampv, attv,
                                                           bmsg, broot, out, N);
    } else {
        gemm_sb<<<ggrid, 1024, 0, stream>>>(Zhi, Zlo, Whi, Wlo, ampv, attv,
                                            bmsg, broot, out, N);
    }
}

// Round 10
// 351.141 us; speedup vs baseline: 2.2229x; 1.0847x over previous
//
#include <hip/hip_runtime.h>
#include <cmath>

#define IN_CH 128
#define OUT_CH 128
#define KDIM 512           // Z row: x(128) | sum(128) | mean(128) | max(128)
#define NGEMM 384          // W^T rows: permuted (colgroup, wavehalf, section, ocol16)
#define GBM 256            // gemm rows per block
#define GBN 192            // gemm cols (W^T rows) per block
#define SLOT_B 40960       // ring slot bytes: Ahi 16K | Bhi 12K | Blo 12K
#define SLOT_US 20480      // ring slot ushorts
#define PIPE_LDS_BYTES (3 * SLOT_B + 24)   // D=3 ring + 6 flag ints

typedef __attribute__((ext_vector_type(8))) short bfrag;   // 8 bf16 in 4 VGPRs
typedef __attribute__((ext_vector_type(4))) float f32x4;

// float -> bf16 round-to-nearest-even (bit pattern)
__device__ __forceinline__ unsigned short f2bf(float f) {
    unsigned int u = __float_as_uint(f);
    return (unsigned short)((u + 0x7FFFu + ((u >> 16) & 1u)) >> 16);
}
__device__ __forceinline__ float bf2f(unsigned short h) {
    return __uint_as_float(((unsigned int)h) << 16);
}
__device__ __forceinline__ float4 unpack4(uint2 u) {
    float4 r;
    r.x = __uint_as_float(u.x << 16);
    r.y = __uint_as_float(u.x & 0xFFFF0000u);
    r.z = __uint_as_float(u.y << 16);
    r.w = __uint_as_float(u.y & 0xFFFF0000u);
    return r;
}

// async 16B global->LDS (wave-level; LDS side is lane-linear base+lane*16)
__device__ __forceinline__ void gl2lds16(const void* g, void* l) {
    __builtin_amdgcn_global_load_lds(
        (const __attribute__((address_space(1))) unsigned int*)g,
        (__attribute__((address_space(3))) unsigned int*)l, 16, 0, 0);
}

// ---------------- CSR build ----------------

__global__ void degree_kernel(const int* __restrict__ ei, int* __restrict__ degree, int E) {
    int e = blockIdx.x * blockDim.x + threadIdx.x;
    if (e < E) atomicAdd(&degree[ei[E + e]], 1);
}

__global__ __launch_bounds__(1024) void scan_kernel(const int* __restrict__ degree,
                                                    int* __restrict__ offsets,
                                                    float* __restrict__ logsum, int n) {
    const int T = 1024;
    int tid = threadIdx.x;
    int chunk = (n + T - 1) / T;
    int beg = min(tid * chunk, n);
    int end = min(beg + chunk, n);
    int s = 0;
    float ls = 0.f;
    for (int i = beg; i < end; ++i) {
        int d = degree[i];
        s += d;
        ls += logf((float)d + 2.0f);   // == log1p(d+1)
    }
    __shared__ int part[T];
    __shared__ float fl[T];
    part[tid] = s;
    fl[tid] = ls;
    __syncthreads();
    for (int off = 1; off < T; off <<= 1) {
        int v = (tid >= off) ? part[tid - off] : 0;
        __syncthreads();
        part[tid] += v;
        __syncthreads();
    }
    for (int off = T / 2; off > 0; off >>= 1) {
        if (tid < off) fl[tid] += fl[tid + off];
        __syncthreads();
    }
    if (tid == 0) logsum[0] = fl[0];
    int prefix = (tid == 0) ? 0 : part[tid - 1];
    for (int i = beg; i < end; ++i) {
        offsets[i] = prefix;
        prefix += degree[i];
    }
    if (tid == T - 1) offsets[n] = prefix;
}

// fill bumps offsets[] in place; afterwards offsets[v] == end of v's segment.
__global__ void fill_kernel(const int* __restrict__ ei, int* __restrict__ offsets,
                            int* __restrict__ csr_src, int E) {
    int e = blockIdx.x * blockDim.x + threadIdx.x;
    if (e < E) {
        int src = ei[e];
        int dst = ei[E + e];
        int pos = atomicAdd(&offsets[dst], 1);
        csr_src[pos] = src;
    }
}

// ---------------- x -> bf16 cast (halves agg gather bytes) ----------------

__global__ void xcast_kernel(const float* __restrict__ x, unsigned short* __restrict__ xb,
                             int total4) {
    int i = blockIdx.x * 256 + threadIdx.x;    // 4 elements each
    if (i >= total4) return;
    float4 v = ((const float4*)x)[i];
    uint2 p;
    p.x = (unsigned)f2bf(v.x) | ((unsigned)f2bf(v.y) << 16);
    p.y = (unsigned)f2bf(v.z) | ((unsigned)f2bf(v.w) << 16);
    ((uint2*)xb)[i] = p;
}

// ---------------- Aggregation: one WAVE per node, bf16 edge-pair gathers ---------
// lane = (h, c4): h = lane>>5 edge-of-pair, c4 = lane&31 -> 4 channels (8 B/lane).
// Accumulate fp32; write Zhi ONLY (A-lo plane dropped; see gemm numerics note).

__global__ __launch_bounds__(256) void agg_kernel(const unsigned short* __restrict__ xb,
                                                  const int* __restrict__ csr_src,
                                                  const int* __restrict__ offsets,
                                                  const int* __restrict__ degree,
                                                  const float* __restrict__ logsum,
                                                  unsigned short* __restrict__ Zhi,
                                                  float* __restrict__ ampv,
                                                  float* __restrict__ attv,
                                                  int N, int Mpad) {
    int node = (blockIdx.x * 256 + threadIdx.x) >> 6;
    int lane = threadIdx.x & 63;
    if (node >= Mpad) return;
    int h = lane >> 5;
    int c4 = lane & 31;
    long zbase = (long)node * KDIM + c4 * 4;
    if (node >= N) {   // pad rows: zero so GEMM reads are harmless
        if (h == 0) {
            uint2 z = make_uint2(0u, 0u);
            #pragma unroll
            for (int sec = 0; sec < 4; ++sec) *(uint2*)&Zhi[zbase + sec * 128] = z;
        }
        return;
    }
    int deg = degree[node];
    int end = offsets[node];          // post-fill end of segment
    int beg = end - deg;
    const float NEG = -3.402823466e38f;
    float4 s[4], m[4];
    #pragma unroll
    for (int u = 0; u < 4; ++u) {
        s[u] = make_float4(0.f, 0.f, 0.f, 0.f);
        m[u] = make_float4(NEG, NEG, NEG, NEG);
    }
    int i = beg;
    for (; i + 8 <= end; i += 8) {      // 4 pair-slots = 8 edges, 4 indep chains
        int idx[4];
        #pragma unroll
        for (int u = 0; u < 4; ++u) idx[u] = csr_src[i + u * 2 + h];
        uint2 raw[4];
        #pragma unroll
        for (int u = 0; u < 4; ++u) raw[u] = *(const uint2*)&xb[(long)idx[u] * IN_CH + c4 * 4];
        #pragma unroll
        for (int u = 0; u < 4; ++u) {
            float4 v = unpack4(raw[u]);
            s[u].x += v.x; s[u].y += v.y; s[u].z += v.z; s[u].w += v.w;
            m[u].x = fmaxf(m[u].x, v.x); m[u].y = fmaxf(m[u].y, v.y);
            m[u].z = fmaxf(m[u].z, v.z); m[u].w = fmaxf(m[u].w, v.w);
        }
    }
    for (; i < end; i += 2) {           // tail pairs (upper half may be inactive)
        int e = i + h;
        if (e < end) {
            float4 v = unpack4(*(const uint2*)&xb[(long)csr_src[e] * IN_CH + c4 * 4]);
            s[0].x += v.x; s[0].y += v.y; s[0].z += v.z; s[0].w += v.w;
            m[0].x = fmaxf(m[0].x, v.x); m[0].y = fmaxf(m[0].y, v.y);
            m[0].z = fmaxf(m[0].z, v.z); m[0].w = fmaxf(m[0].w, v.w);
        }
    }
    float4 sum, mx;
    sum.x = (s[0].x + s[1].x) + (s[2].x + s[3].x);
    sum.y = (s[0].y + s[1].y) + (s[2].y + s[3].y);
    sum.z = (s[0].z + s[1].z) + (s[2].z + s[3].z);
    sum.w = (s[0].w + s[1].w) + (s[2].w + s[3].w);
    mx.x = fmaxf(fmaxf(m[0].x, m[1].x), fmaxf(m[2].x, m[3].x));
    mx.y = fmaxf(fmaxf(m[0].y, m[1].y), fmaxf(m[2].y, m[3].y));
    mx.z = fmaxf(fmaxf(m[0].z, m[1].z), fmaxf(m[2].z, m[3].z));
    mx.w = fmaxf(fmaxf(m[0].w, m[1].w), fmaxf(m[2].w, m[3].w));
    // cross-half combine
    sum.x += __shfl_xor(sum.x, 32); sum.y += __shfl_xor(sum.y, 32);
    sum.z += __shfl_xor(sum.z, 32); sum.w += __shfl_xor(sum.w, 32);
    mx.x = fmaxf(mx.x, __shfl_xor(mx.x, 32)); mx.y = fmaxf(mx.y, __shfl_xor(mx.y, 32));
    mx.z = fmaxf(mx.z, __shfl_xor(mx.z, 32)); mx.w = fmaxf(mx.w, __shfl_xor(mx.w, 32));

    float inv = 1.0f / fmaxf((float)deg, 1.0f);
    float4 mean = make_float4(sum.x * inv, sum.y * inv, sum.z * inv, sum.w * inv);
    if (deg == 0) mx = make_float4(0.f, 0.f, 0.f, 0.f);
    float4 xv = unpack4(*(const uint2*)&xb[(long)node * IN_CH + c4 * 4]);

    if (h == 0) {
        float4 secs[4] = { xv, sum, mean, mx };
        #pragma unroll
        for (int sec = 0; sec < 4; ++sec) {
            float4 v = secs[sec];
            uint2 hi;
            hi.x = (unsigned)f2bf(v.x) | ((unsigned)f2bf(v.y) << 16);
            hi.y = (unsigned)f2bf(v.z) | ((unsigned)f2bf(v.w) << 16);
            *(uint2*)&Zhi[zbase + sec * 128] = hi;
        }
    }
    if (lane == 0) {
        float ref = fmaxf(logsum[0] / (float)N, 1.0f);
        float dt = log1pf((float)deg + 1.0f);
        ampv[node] = dt / ref;
        attv[node] = ref / fmaxf(dt, 1e-6f);
    }
}

// ---------------- Weight build: permuted row-major W^T, bf16 hi/lo -----------------

__global__ void wbuild_kernel(const float* __restrict__ Wmsg, const float* __restrict__ Wroot,
                              unsigned short* __restrict__ Whi, unsigned short* __restrict__ Wlo) {
    int idx = blockIdx.x * 256 + threadIdx.x;
    if (idx >= NGEMM * KDIM) return;
    int jp = idx >> 9;       // 0..383
    int k = idx & 511;
    int cg = jp / 96;
    int rem = jp - cg * 96;
    int s16 = rem >> 4;
    int r16 = rem & 15;
    int wn2 = s16 / 3;
    int sec = s16 - wn2 * 3;
    int ocol = cg * 32 + wn2 * 16 + r16;
    float v;
    if (k < 128) {
        v = (sec == 0) ? Wroot[ocol * 128 + k] : 0.f;
    } else {
        int a = (k - 128) >> 7;
        int c = (k - 128) & 127;
        v = Wmsg[ocol * 1152 + (a * 3 + sec) * 128 + c];
    }
    unsigned short h = f2bf(v);
    Whi[idx] = h;
    Wlo[idx] = f2bf(v - bf2f(h));
}

// ---------------- MFMA GEMM, depth-3 ring, vmcnt(L) waits (never drains) -----------
// Numerics: out = Ahi*(Bhi+Blo): A bf16, B ~fp32-split. Alo product dropped (r10):
// ~1e-3 abs error, saves 100 MB staged + 1/3 of MFMAs.
// Per wave, iter i (slot s=i%3), steady state has stages i,i+1 in flight:
//   1. s_waitcnt vmcnt(L)     -- L = own loads/stage; in-order retire => stage(i) landed
//   2. ready[s]++ (lane 0)
//   3. spin done[(i+2)%3] >= 16*((i+2)/3), FIRE stage(i+2) (not waited)
//   4. spin ready[s] >= 16*(i/3+1), ds_read frags, 24 MFMA
//   5. done[s]++ (lane 0)
// LDS slot (chunks of 16B): Ahi [0,1024) | Bhi+Blo [1024,2560).

__global__ __launch_bounds__(1024, 4) void gemm_pipe(const unsigned short* __restrict__ Zhi,
                                                     const unsigned short* __restrict__ Whi,
                                                     const unsigned short* __restrict__ Wlo,
                                                     const float* __restrict__ ampv,
                                                     const float* __restrict__ attv,
                                                     const float* __restrict__ bmsg,
                                                     const float* __restrict__ broot,
                                                     float* __restrict__ out, int M) {
    extern __shared__ char smem[];
    unsigned short* lds = (unsigned short*)smem;
    int* flags = (int*)(smem + 3 * SLOT_B);   // ready[3], done[3]
    volatile int* vf = (volatile int*)flags;
    const int tid = threadIdx.x;
    const int w = tid >> 6;                 // 0..15
    const int lane = tid & 63;
    const int r16 = lane & 15, q = lane >> 4;
    const int wm = w >> 2, wn = w & 3;
    const int row0 = blockIdx.x * GBM;
    const int cg2 = blockIdx.y;             // 0..1

    if (tid == 0) {
        #pragma unroll
        for (int f = 0; f < 6; ++f) flags[f] = 0;
    }
    __syncthreads();                        // only barrier; nothing in flight yet

    const unsigned short* sAh = Zhi + (long)(row0 + w * 16 + r16) * KDIM + q * 8;
    const unsigned short* sB2 = (w < 12)
        ? Whi + (long)(cg2 * GBN + w * 16 + r16) * KDIM + q * 8
        : Wlo + (long)(cg2 * GBN + (w - 12) * 16 + r16) * KDIM + q * 8;
    const unsigned short* sB3 = Wlo + (long)(cg2 * GBN + (4 + w) * 16 + r16) * KDIM + q * 8;
    const int d0 = tid * 16, d2 = (1024 + tid) * 16, d3 = (2048 + tid) * 16;

    // prologue: stage 0 -> slot 0, stage 1 -> slot 1
    gl2lds16(sAh, smem + d0); gl2lds16(sB2, smem + d2); if (w < 8) gl2lds16(sB3, smem + d3);
    sAh += 32; sB2 += 32; sB3 += 32;
    gl2lds16(sAh, smem + SLOT_B + d0); gl2lds16(sB2, smem + SLOT_B + d2);
    if (w < 8) gl2lds16(sB3, smem + SLOT_B + d3);
    sAh += 32; sB2 += 32; sB3 += 32;

    f32x4 acc[4][3] = {};
    const int jtb = (wn >> 1) * 6 + (wn & 1) * 3;

    for (int it = 0; it < 16; ++it) {
        const int s = it % 3;
        if (it == 15)      __builtin_amdgcn_s_waitcnt(0x0F70);   // vmcnt(0): last stage
        else if (w < 8)    __builtin_amdgcn_s_waitcnt(0x0F73);   // vmcnt(3): own L=3
        else               __builtin_amdgcn_s_waitcnt(0x0F72);   // vmcnt(2): own L=2
        if (lane == 0) atomicAdd(&flags[s], 1);                  // ready[s]++
        const int j = it + 2;
        if (j < 16) {
            const int s2 = j % 3;
            const int needd = 16 * (j / 3);                      // occupant j-3 consumed
            if (needd) { while (vf[3 + s2] < needd) {} }
            char* b = smem + s2 * SLOT_B;
            gl2lds16(sAh, b + d0); gl2lds16(sB2, b + d2); if (w < 8) gl2lds16(sB3, b + d3);
            sAh += 32; sB2 += 32; sB3 += 32;
        }
        const int needr = 16 * (it / 3 + 1);
        while (vf[s] < needr) {}                                 // all 16 waves staged
        const unsigned short* L = lds + s * SLOT_US;

        bfrag bh[3], bl[3];
        #pragma unroll
        for (int nt = 0; nt < 3; ++nt) {
            int chb = (jtb + nt) * 512 + lane * 8;
            bh[nt] = *(const bfrag*)&L[8192 + chb];
            bl[nt] = *(const bfrag*)&L[14336 + chb];
        }
        #pragma unroll
        for (int mt = 0; mt < 4; ++mt) {
            bfrag ah = *(const bfrag*)&L[((wm * 4 + mt) * 64 + lane) * 8];
            #pragma unroll
            for (int nt = 0; nt < 3; ++nt) {
                acc[mt][nt] = __builtin_amdgcn_mfma_f32_16x16x32_bf16(ah, bh[nt], acc[mt][nt], 0, 0, 0);
                acc[mt][nt] = __builtin_amdgcn_mfma_f32_16x16x32_bf16(ah, bl[nt], acc[mt][nt], 0, 0, 0);
            }
        }
        if (lane == 0) atomicAdd(&flags[3 + s], 1);              // done[s]++
    }

    // fused epilogue: C/D layout col=lane&15, row=q*4+r (verified m89/m91)
    const int col = (cg2 * 2 + (wn >> 1)) * 32 + (wn & 1) * 16 + r16;
    const float bias = bmsg[col] + broot[col];
    #pragma unroll
    for (int mt = 0; mt < 4; ++mt) {
        #pragma unroll
        for (int r = 0; r < 4; ++r) {
            int row = row0 + wm * 64 + mt * 16 + q * 4 + r;
            if (row < M) {
                float v = acc[mt][0][r]
                        + ampv[row] * acc[mt][1][r]
                        + attv[row] * acc[mt][2][r] + bias;
                out[(long)row * OUT_CH + col] = v;
            }
        }
    }
}

// ---------------- fallback: single-buffer (static 40 KB), barriers -----------------

__global__ __launch_bounds__(1024, 4) void gemm_sb(const unsigned short* __restrict__ Zhi,
                                                   const unsigned short* __restrict__ Whi,
                                                   const unsigned short* __restrict__ Wlo,
                                                   const float* __restrict__ ampv,
                                                   const float* __restrict__ attv,
                                                   const float* __restrict__ bmsg,
                                                   const float* __restrict__ broot,
                                                   float* __restrict__ out, int M) {
    __shared__ unsigned short lds[SLOT_US];   // 40 KB
    const int tid = threadIdx.x;
    const int w = tid >> 6;
    const int lane = tid & 63;
    const int r16 = lane & 15, q = lane >> 4;
    const int wm = w >> 2, wn = w & 3;
    const int row0 = blockIdx.x * GBM;
    const int cg2 = blockIdx.y;

    const unsigned short* sAh = Zhi + (long)(row0 + w * 16 + r16) * KDIM + q * 8;
    const unsigned short* sB2 = (w < 12)
        ? Whi + (long)(cg2 * GBN + w * 16 + r16) * KDIM + q * 8
        : Wlo + (long)(cg2 * GBN + (w - 12) * 16 + r16) * KDIM + q * 8;
    const unsigned short* sB3 = Wlo + (long)(cg2 * GBN + (4 + w) * 16 + r16) * KDIM + q * 8;
    char* ldsb = (char*)lds;
    const int d0 = tid * 16, d2 = (1024 + tid) * 16, d3 = (2048 + tid) * 16;

    f32x4 acc[4][3] = {};
    const int jtb = (wn >> 1) * 6 + (wn & 1) * 3;

    #pragma unroll 1
    for (int it = 0; it < 16; ++it) {
        if (it) __syncthreads();
        gl2lds16(sAh, ldsb + d0); gl2lds16(sB2, ldsb + d2); if (w < 8) gl2lds16(sB3, ldsb + d3);
        sAh += 32; sB2 += 32; sB3 += 32;
        __syncthreads();

        bfrag bh[3], bl[3];
        #pragma unroll
        for (int nt = 0; nt < 3; ++nt) {
            int chb = (jtb + nt) * 512 + lane * 8;
            bh[nt] = *(const bfrag*)&lds[8192 + chb];
            bl[nt] = *(const bfrag*)&lds[14336 + chb];
        }
        #pragma unroll
        for (int mt = 0; mt < 4; ++mt) {
            bfrag ah = *(const bfrag*)&lds[((wm * 4 + mt) * 64 + lane) * 8];
            #pragma unroll
            for (int nt = 0; nt < 3; ++nt) {
                acc[mt][nt] = __builtin_amdgcn_mfma_f32_16x16x32_bf16(ah, bh[nt], acc[mt][nt], 0, 0, 0);
                acc[mt][nt] = __builtin_amdgcn_mfma_f32_16x16x32_bf16(ah, bl[nt], acc[mt][nt], 0, 0, 0);
            }
        }
    }

    const int col = (cg2 * 2 + (wn >> 1)) * 32 + (wn & 1) * 16 + r16;
    const float bias = bmsg[col] + broot[col];
    #pragma unroll
    for (int mt = 0; mt < 4; ++mt) {
        #pragma unroll
        for (int r = 0; r < 4; ++r) {
            int row = row0 + wm * 64 + mt * 16 + q * 4 + r;
            if (row < M) {
                float v = acc[mt][0][r]
                        + ampv[row] * acc[mt][1][r]
                        + attv[row] * acc[mt][2][r] + bias;
                out[(long)row * OUT_CH + col] = v;
            }
        }
    }
}

// ---------------- Launch ----------------

extern "C" void kernel_launch(void* const* d_in, const int* in_sizes, int n_in,
                              void* d_out, int out_size, void* d_ws, size_t ws_size,
                              hipStream_t stream) {
    const float* x     = (const float*)d_in[0];
    const int*   ei    = (const int*)d_in[1];
    const float* Wmsg  = (const float*)d_in[2];
    const float* bmsg  = (const float*)d_in[3];
    const float* Wroot = (const float*)d_in[4];
    const float* broot = (const float*)d_in[5];
    float* out = (float*)d_out;

    int N = in_sizes[0] / IN_CH;           // 50000
    int E = in_sizes[1] / 2;               // 600000
    int Mb = (N + GBM - 1) / GBM;          // 196
    int Mpad = Mb * GBM;                   // 50176

    char* ws = (char*)d_ws;
    size_t off = 0;
    auto alloc = [&](size_t bytes) -> void* {
        void* p = ws + off;
        off = (off + bytes + 255) & ~(size_t)255;
        return p;
    };
    int* degree  = (int*)alloc((size_t)N * 4);
    int* offsets = (int*)alloc((size_t)(N + 1) * 4);
    float* logsum = (float*)alloc(4);
    int* csr_src = (int*)alloc((size_t)E * 4);
    unsigned short* Whi = (unsigned short*)alloc((size_t)NGEMM * KDIM * 2);
    unsigned short* Wlo = (unsigned short*)alloc((size_t)NGEMM * KDIM * 2);
    unsigned short* Zhi = (unsigned short*)alloc((size_t)Mpad * KDIM * 2);
    unsigned short* xb  = (unsigned short*)alloc((size_t)Mpad * IN_CH * 2);
    float* ampv = (float*)alloc((size_t)N * 4);
    float* attv = (float*)alloc((size_t)N * 4);

    hipMemsetAsync(degree, 0, (size_t)N * 4, stream);

    degree_kernel<<<(E + 255) / 256, 256, 0, stream>>>(ei, degree, E);
    xcast_kernel<<<(N * IN_CH / 4 + 255) / 256, 256, 0, stream>>>(x, xb, N * IN_CH / 4);
    scan_kernel<<<1, 1024, 0, stream>>>(degree, offsets, logsum, N);
    fill_kernel<<<(E + 255) / 256, 256, 0, stream>>>(ei, offsets, csr_src, E);
    agg_kernel<<<(Mpad * 64 + 255) / 256, 256, 0, stream>>>(xb, csr_src, offsets, degree, logsum,
                                                            Zhi, ampv, attv, N, Mpad);
    wbuild_kernel<<<(NGEMM * KDIM + 255) / 256, 256, 0, stream>>>(Wmsg, Wroot, Whi, Wlo);

    // device-capability branch (deterministic per device; capture-safe host queries)
    bool pipe = false;
    int dev = 0;
    if (hipGetDevice(&dev) == hipSuccess) {
        int optin = 0;
        if (hipDeviceGetAttribute(&optin, hipDeviceAttributeSharedMemPerBlockOptin, dev) == hipSuccess
            && optin >= (int)PIPE_LDS_BYTES) {
            pipe = (hipFuncSetAttribute((const void*)gemm_pipe,
                                        hipFuncAttributeMaxDynamicSharedMemorySize,
                                        PIPE_LDS_BYTES) == hipSuccess);
        }
    }
    dim3 ggrid(Mb, 2);
    if (pipe) {
        gemm_pipe<<<ggrid, 1024, PIPE_LDS_BYTES, stream>>>(Zhi, Whi, Wlo, ampv, attv,
                                                           bmsg, broot, out, N);
    } else {
        gemm_sb<<<ggrid, 1024, 0, stream>>>(Zhi, Whi, Wlo, ampv, attv,
                                            bmsg, broot, out, N);
    }
}